// Round 2
// baseline (3199.753 us; speedup 1.0000x reference)
//
#include <hip/hip_runtime.h>
#include <math.h>

#define N_PTS 150000
#define F_DIM 512
#define S_SEG 5000
#define K_KEY 512
#define H_HEADS 4
#define DH 128
#define OUT_DIM 20
#define TWO_PI 6.28318530717958647692f

// ---------- helpers ----------
__device__ __forceinline__ unsigned enc_key(float f){
  unsigned u = __float_as_uint(f);
  return (u & 0x80000000u) ? ~u : (u | 0x80000000u);
}
__device__ __forceinline__ float dec_key(unsigned k){
  return __uint_as_float((k & 0x80000000u) ? (k ^ 0x80000000u) : ~k);
}
__device__ __forceinline__ float block_sum(float v, float* lds){
#pragma unroll
  for (int off = 32; off > 0; off >>= 1) v += __shfl_xor(v, off);
  __syncthreads();
  if ((threadIdx.x & 63) == 0) lds[threadIdx.x >> 6] = v;
  __syncthreads();
  return lds[0] + lds[1] + lds[2] + lds[3];
}
__device__ __forceinline__ float block_max(float v, float* lds){
#pragma unroll
  for (int off = 32; off > 0; off >>= 1) v = fmaxf(v, __shfl_xor(v, off));
  __syncthreads();
  if ((threadIdx.x & 63) == 0) lds[threadIdx.x >> 6] = v;
  __syncthreads();
  return fmaxf(fmaxf(lds[0], lds[1]), fmaxf(lds[2], lds[3]));
}

// ---------- stage 0: init ----------
__global__ void init_kernel(unsigned* mm, int* cnt){
  int t = blockIdx.x * 256 + threadIdx.x;
  if (t < S_SEG) cnt[t] = 0;
  if (t < 3) mm[t] = 0xFFFFFFFFu;      // min init (encoded)
  else if (t < 6) mm[t] = 0u;          // max init (encoded)
}

// ---------- stage 1: coord min/max ----------
__global__ __launch_bounds__(256) void minmax_kernel(const float* __restrict__ coords,
                                                     unsigned* __restrict__ mm){
  int t = blockIdx.x * blockDim.x + threadIdx.x;
  int stride = gridDim.x * blockDim.x;
  float mn[3] = {1e30f, 1e30f, 1e30f}, mx[3] = {-1e30f, -1e30f, -1e30f};
  for (int i = t; i < N_PTS; i += stride){
#pragma unroll
    for (int d = 0; d < 3; ++d){
      float v = coords[3 * i + d];
      mn[d] = fminf(mn[d], v);
      mx[d] = fmaxf(mx[d], v);
    }
  }
#pragma unroll
  for (int off = 32; off > 0; off >>= 1){
#pragma unroll
    for (int d = 0; d < 3; ++d){
      mn[d] = fminf(mn[d], __shfl_xor(mn[d], off));
      mx[d] = fmaxf(mx[d], __shfl_xor(mx[d], off));
    }
  }
  if ((threadIdx.x & 63) == 0){
#pragma unroll
    for (int d = 0; d < 3; ++d){
      atomicMin(&mm[d], enc_key(mn[d]));
      atomicMax(&mm[3 + d], enc_key(mx[d]));
    }
  }
}

// ---------- stage 2: CSR build ----------
__global__ void hist_kernel(const int* __restrict__ seg, int* __restrict__ cnt){
  int i = blockIdx.x * 256 + threadIdx.x;
  if (i < N_PTS) atomicAdd(&cnt[seg[i]], 1);
}

__global__ __launch_bounds__(1024) void scan_kernel(const int* __restrict__ cnt,
                                                    int* __restrict__ offsets,
                                                    int* __restrict__ cursor){
  __shared__ int buf0[1024], buf1[1024];
  const int t = threadIdx.x;
  int v[5]; int s = 0;
#pragma unroll
  for (int e = 0; e < 5; ++e){
    int j = t * 5 + e;
    v[e] = (j < S_SEG) ? cnt[j] : 0;
    s += v[e];
  }
  buf0[t] = s;
  __syncthreads();
  int* src = buf0; int* dst = buf1;
  for (int off = 1; off < 1024; off <<= 1){
    int x = src[t];
    if (t >= off) x += src[t - off];
    dst[t] = x;
    __syncthreads();
    int* tm = src; src = dst; dst = tm;
  }
  int incl = src[t];
  int ex = incl - s;
#pragma unroll
  for (int e = 0; e < 5; ++e){
    int j = t * 5 + e;
    if (j < S_SEG){ offsets[j] = ex; cursor[j] = 0; ex += v[e]; }
  }
  if (t == 1023) offsets[S_SEG] = incl;
}

__global__ void fill_kernel(const int* __restrict__ seg, const int* __restrict__ offsets,
                            int* __restrict__ cursor, int* __restrict__ bucket){
  int i = blockIdx.x * 256 + threadIdx.x;
  if (i < N_PTS){
    int s = seg[i];
    int p = atomicAdd(&cursor[s], 1);
    bucket[offsets[s] + p] = i;
  }
}

// ---------- stage 3: segment pooling (feat + recomputed fourier PE), fused norms ----------
__global__ __launch_bounds__(256) void pool_kernel(
    const float* __restrict__ coords, const float* __restrict__ pf,
    const float* __restrict__ fB, const int* __restrict__ bucket,
    const int* __restrict__ offsets, const unsigned* __restrict__ mm,
    float* __restrict__ seg_feat, float* __restrict__ seg_pos,
    float* __restrict__ norms){
  __shared__ float Bs[768];
  __shared__ float lds[4];
  int s = blockIdx.x, t = threadIdx.x;
  for (int k = t; k < 768; k += 256) Bs[k] = fB[k];
  float mn[3], iv[3];
#pragma unroll
  for (int d = 0; d < 3; ++d){
    mn[d] = dec_key(mm[d]);
    float mxd = dec_key(mm[3 + d]);
    iv[d] = 1.0f / (mxd - mn[d] + 1e-6f);
  }
  int st = offsets[s], en = offsets[s + 1];
  float fs0 = 0, fs1 = 0, ps0 = 0, ps1 = 0;
  __syncthreads();
  for (int p = st; p < en; ++p){
    int i = bucket[p];
    float c0 = coords[3 * i], c1 = coords[3 * i + 1], c2 = coords[3 * i + 2];
    float n0 = (c0 - mn[0]) * iv[0];
    float n1 = (c1 - mn[1]) * iv[1];
    float n2 = (c2 - mn[2]) * iv[2];
    float proj = TWO_PI * (n0 * Bs[t] + n1 * Bs[256 + t] + n2 * Bs[512 + t]);
    float sv, cv; sincosf(proj, &sv, &cv);
    ps0 += sv; ps1 += cv;
    fs0 += pf[(size_t)i * 512 + t];
    fs1 += pf[(size_t)i * 512 + t + 256];
  }
  float invc = 1.0f / fmaxf((float)(en - st), 1.0f);
  fs0 *= invc; fs1 *= invc; ps0 *= invc; ps1 *= invc;
  seg_feat[(size_t)s * 512 + t] = fs0;
  seg_feat[(size_t)s * 512 + t + 256] = fs1;
  seg_pos[(size_t)s * 512 + t] = ps0;
  seg_pos[(size_t)s * 512 + t + 256] = ps1;
  float nr = block_sum(ps0 * ps0 + ps1 * ps1, lds);
  if (t == 0) norms[s] = nr;
}

// ---------- generic fp32 GEMMs (64x64 tile, 4x4/thread, BK=32, k-unrolled b128 LDS reads) ----------
// NT: C[m][n] = scale * sum_k A[m][k]*B[n][k]   (+ optional symmetric mirror)
__global__ __launch_bounds__(256) void gemm_nt(
    const float* __restrict__ A, int lda, size_t saz,
    const float* __restrict__ B, int ldb, size_t sbz,
    float* __restrict__ C, int ldc, size_t scz,
    int M, int N, int K, float scale, int sym){
  A += blockIdx.z * saz; B += blockIdx.z * sbz; C += blockIdx.z * scz;
  const int m0 = blockIdx.x * 64, n0 = blockIdx.y * 64;
  if (sym && (n0 + 63 < m0)) return;   // lower tiles filled by mirror
  __shared__ float As[64][36], Bs[64][36];
  const int tid = threadIdx.x;
  const int tx = tid & 15, ty = tid >> 4;
  const int lr = tid >> 2, lq = tid & 3;
  float acc[4][4] = {{0}};
  for (int kb = 0; kb < K; kb += 32){
    {
      int m = m0 + lr;
      float4 z = {0, 0, 0, 0};
      float4 v0 = z, v1 = z;
      if (m < M){
        v0 = *(const float4*)(A + (size_t)m * lda + kb + lq * 4);
        v1 = *(const float4*)(A + (size_t)m * lda + kb + lq * 4 + 16);
      }
      *(float4*)&As[lr][lq * 4] = v0;
      *(float4*)&As[lr][lq * 4 + 16] = v1;
      int n = n0 + lr;
      float4 w0 = z, w1 = z;
      if (n < N){
        w0 = *(const float4*)(B + (size_t)n * ldb + kb + lq * 4);
        w1 = *(const float4*)(B + (size_t)n * ldb + kb + lq * 4 + 16);
      }
      *(float4*)&Bs[lr][lq * 4] = w0;
      *(float4*)&Bs[lr][lq * 4 + 16] = w1;
    }
    __syncthreads();
#pragma unroll
    for (int kk = 0; kk < 8; ++kk){
      alignas(16) float a[4][4], b[4][4];
#pragma unroll
      for (int i = 0; i < 4; ++i) *(float4*)a[i] = *(const float4*)&As[ty * 4 + i][kk * 4];
#pragma unroll
      for (int j = 0; j < 4; ++j) *(float4*)b[j] = *(const float4*)&Bs[tx * 4 + j][kk * 4];
#pragma unroll
      for (int i = 0; i < 4; ++i)
#pragma unroll
        for (int j = 0; j < 4; ++j)
#pragma unroll
          for (int p = 0; p < 4; ++p)
            acc[i][j] += a[i][p] * b[j][p];
    }
    __syncthreads();
  }
#pragma unroll
  for (int i = 0; i < 4; ++i){
    int m = m0 + ty * 4 + i;
    if (m >= M) continue;
#pragma unroll
    for (int j = 0; j < 4; ++j){
      int n = n0 + tx * 4 + j;
      if (n >= N) continue;
      float v = acc[i][j] * scale;
      C[(size_t)m * ldc + n] = v;
      if (sym) C[(size_t)n * ldc + m] = v;
    }
  }
}

// NN: C[m][n] = sum_k A[m][k]*W[k][n] (+bias[n]) (+res[m][n])
__global__ __launch_bounds__(256) void gemm_nn(
    const float* __restrict__ A, int lda, size_t saz,
    const float* __restrict__ W, int ldw, size_t swz,
    const float* __restrict__ bias,
    const float* __restrict__ res, int ldres,
    float* __restrict__ C, int ldc, size_t scz,
    int M, int N, int K){
  A += blockIdx.z * saz; W += blockIdx.z * swz; C += blockIdx.z * scz;
  __shared__ float As[64][36], Ws[32][68];
  const int tid = threadIdx.x;
  const int tx = tid & 15, ty = tid >> 4;
  const int m0 = blockIdx.x * 64, n0 = blockIdx.y * 64;
  const int lr = tid >> 2, lq = tid & 3;
  const int wk = tid >> 3, wc = tid & 7;
  float acc[4][4] = {{0}};
  for (int kb = 0; kb < K; kb += 32){
    {
      int m = m0 + lr;
      float4 z = {0, 0, 0, 0};
      float4 v0 = z, v1 = z;
      if (m < M){
        v0 = *(const float4*)(A + (size_t)m * lda + kb + lq * 4);
        v1 = *(const float4*)(A + (size_t)m * lda + kb + lq * 4 + 16);
      }
      *(float4*)&As[lr][lq * 4] = v0;
      *(float4*)&As[lr][lq * 4 + 16] = v1;
      float4 w0 = *(const float4*)(W + (size_t)(kb + wk) * ldw + n0 + wc * 4);
      float4 w1 = *(const float4*)(W + (size_t)(kb + wk) * ldw + n0 + wc * 4 + 32);
      *(float4*)&Ws[wk][wc * 4] = w0;
      *(float4*)&Ws[wk][wc * 4 + 32] = w1;
    }
    __syncthreads();
#pragma unroll
    for (int kk = 0; kk < 8; ++kk){
      alignas(16) float a[4][4], w[4][4];
#pragma unroll
      for (int i = 0; i < 4; ++i) *(float4*)a[i] = *(const float4*)&As[ty * 4 + i][kk * 4];
#pragma unroll
      for (int p = 0; p < 4; ++p) *(float4*)w[p] = *(const float4*)&Ws[kk * 4 + p][tx * 4];
#pragma unroll
      for (int i = 0; i < 4; ++i)
#pragma unroll
        for (int j = 0; j < 4; ++j)
#pragma unroll
          for (int p = 0; p < 4; ++p)
            acc[i][j] += a[i][p] * w[p][j];
    }
    __syncthreads();
  }
#pragma unroll
  for (int i = 0; i < 4; ++i){
    int m = m0 + ty * 4 + i;
    if (m >= M) continue;
#pragma unroll
    for (int j = 0; j < 4; ++j){
      int n = n0 + tx * 4 + j;
      if (n >= N) continue;
      float v = acc[i][j];
      if (bias) v += bias[n];
      if (res) v += res[(size_t)m * ldres + n];
      C[(size_t)m * ldc + n] = v;
    }
  }
}

// ---------- stage 4: FPS (single block; Gram-row per iteration, register-resident dmin) ----------
__global__ __launch_bounds__(1024) void fps_kernel(const float* __restrict__ gram,
                                                   const float* __restrict__ norms,
                                                   int* __restrict__ fps_idx){
  __shared__ unsigned long long red[16];
  __shared__ int scur;
  const int t = threadIdx.x;
  float m[5], nj[5];
#pragma unroll
  for (int i = 0; i < 5; ++i){
    m[i] = 1e10f;
    int j = t + i * 1024;
    nj[i] = (j < S_SEG) ? norms[j] : 0.0f;
  }
  int cur = 0;
  for (int it = 0; it < K_KEY; ++it){
    if (t == 0) fps_idx[it] = cur;
    const float ncur = norms[cur];
    const float* grow = gram + (size_t)cur * S_SEG;
    unsigned long long best = 0ULL;
#pragma unroll
    for (int i = 0; i < 5; ++i){
      int j = t + i * 1024;
      if (j < S_SEG){
        float d = nj[i] + ncur - 2.0f * grow[j];
        m[i] = fminf(m[i], d);
        unsigned u = enc_key(m[i]);
        unsigned long long key = ((unsigned long long)u << 32) |
                                 (unsigned long long)(0xFFFFFFFFu - (unsigned)j);
        best = (key > best) ? key : best;
      }
    }
#pragma unroll
    for (int off = 32; off > 0; off >>= 1){
      unsigned long long o = __shfl_xor(best, off);
      best = (o > best) ? o : best;
    }
    if ((t & 63) == 0) red[t >> 6] = best;
    __syncthreads();
    if (t < 64){
      unsigned long long b = (t < 16) ? red[t] : 0ULL;
#pragma unroll
      for (int off = 8; off > 0; off >>= 1){
        unsigned long long o = __shfl_xor(b, off);
        b = (o > b) ? o : b;
      }
      if (t == 0) scur = (int)(0xFFFFFFFFu - (unsigned)(b & 0xFFFFFFFFull));
    }
    __syncthreads();
    cur = scur;
  }
}

// ---------- stage 5: gather keys ----------
__global__ void gather_keys(const int* __restrict__ fps_idx,
                            const float* __restrict__ seg_feat,
                            const float* __restrict__ seg_pos,
                            float* __restrict__ key_feat, float* __restrict__ kin){
  int k = blockIdx.x, t = threadIdx.x;
  int j = fps_idx[k];
  for (int f = t; f < 512; f += 256){
    float kf = seg_feat[(size_t)j * 512 + f];
    key_feat[(size_t)k * 512 + f] = kf;
    kin[(size_t)k * 512 + f] = kf + seg_pos[(size_t)j * 512 + f];
  }
}

// ---------- stage 6: LN + pos add ----------
__global__ __launch_bounds__(256) void ln_add_kernel(
    const float* __restrict__ q, const float* __restrict__ pos,
    const float* __restrict__ g, const float* __restrict__ b,
    float* __restrict__ out){
  __shared__ float lds[4];
  int r = blockIdx.x, t = threadIdx.x;
  const float* row = q + (size_t)r * 512;
  float x0 = row[t], x1 = row[t + 256];
  float s1 = block_sum(x0 + x1, lds);
  float s2 = block_sum(x0 * x0 + x1 * x1, lds);
  float mean = s1 * (1.0f / 512.0f);
  float var = s2 * (1.0f / 512.0f) - mean * mean;
  float inv = rsqrtf(var + 1e-5f);
  out[(size_t)r * 512 + t]       = (x0 - mean) * inv * g[t]       + b[t]       + pos[(size_t)r * 512 + t];
  out[(size_t)r * 512 + t + 256] = (x1 - mean) * inv * g[t + 256] + b[t + 256] + pos[(size_t)r * 512 + t + 256];
}

// ---------- stage 7: row softmax ----------
__global__ __launch_bounds__(256) void softmax_kernel(float* __restrict__ att){
  __shared__ float lds[4];
  int r = blockIdx.x, t = threadIdx.x;
  float* row = att + (size_t)r * 512;
  float x0 = row[t], x1 = row[t + 256];
  float mx = block_max(fmaxf(x0, x1), lds);
  float e0 = expf(x0 - mx), e1 = expf(x1 - mx);
  float s = block_sum(e0 + e1, lds);
  float inv = 1.0f / s;
  row[t] = e0 * inv;
  row[t + 256] = e1 * inv;
}

// ---------- stage 8: fused gather + |diff|-LN + sigmoid blend + classifier ----------
__global__ __launch_bounds__(256) void final_kernel(
    const float* __restrict__ pf, const float* __restrict__ q,
    const int* __restrict__ seg,
    const float* __restrict__ g1, const float* __restrict__ b1,
    const float* __restrict__ w1, const float* __restrict__ b1s,
    const float* __restrict__ cW, const float* __restrict__ cB,
    float* __restrict__ out){
  __shared__ float wcls[512 * 21];          // pad 21: lane stride 21 floats -> conflict-free
  __shared__ float g_s[512], b_s[512], w_s[512];
  int t = threadIdx.x;
  for (int k = t; k < 512 * 20; k += 256){ int f = k / 20, o = k % 20; wcls[f * 21 + o] = cW[k]; }
  for (int k = t; k < 512; k += 256){ g_s[k] = g1[k]; b_s[k] = b1[k]; w_s[k] = w1[k]; }
  __syncthreads();
  const int lane = t & 63, w = t >> 6;
  const float bb = b1s[0];
  for (int p = 0; p < 16; ++p){
    int i = blockIdx.x * 64 + w * 16 + p;
    if (i >= N_PTS) continue;
    const float* pr = pf + (size_t)i * 512;
    const float* qr = q + (size_t)seg[i] * 512;
    float pv[8], fv[8], dv[8];
    float ls = 0, lq = 0;
#pragma unroll
    for (int e = 0; e < 8; ++e){
      int f = lane + 64 * e;
      pv[e] = pr[f];
      fv[e] = qr[f];
      dv[e] = fabsf(fv[e] - pv[e]);
      ls += dv[e];
      lq += dv[e] * dv[e];
    }
#pragma unroll
    for (int off = 32; off > 0; off >>= 1){ ls += __shfl_xor(ls, off); lq += __shfl_xor(lq, off); }
    float mean = ls * (1.0f / 512.0f);
    float var = lq * (1.0f / 512.0f) - mean * mean;
    float inv = rsqrtf(var + 1e-5f);
    float ap = 0;
#pragma unroll
    for (int e = 0; e < 8; ++e){
      int f = lane + 64 * e;
      ap += ((dv[e] - mean) * inv * g_s[f] + b_s[f]) * w_s[f];
    }
#pragma unroll
    for (int off = 32; off > 0; off >>= 1) ap += __shfl_xor(ap, off);
    float wgt = 1.0f / (1.0f + expf(-(ap + bb)));
    float acc[20];
#pragma unroll
    for (int o = 0; o < 20; ++o) acc[o] = 0.0f;
#pragma unroll
    for (int e = 0; e < 8; ++e){
      int f = lane + 64 * e;
      float bl = pv[e] + wgt * (fv[e] - pv[e]);
      const float* wr = &wcls[f * 21];
#pragma unroll
      for (int o = 0; o < 20; ++o) acc[o] += bl * wr[o];
    }
#pragma unroll
    for (int off = 32; off > 0; off >>= 1)
#pragma unroll
      for (int o = 0; o < 20; ++o) acc[o] += __shfl_xor(acc[o], off);
    if (lane == 0){
#pragma unroll
      for (int o = 0; o < 20; ++o) out[(size_t)i * 20 + o] = acc[o] + cB[o];
    }
  }
}

// ---------- host ----------
extern "C" void kernel_launch(void* const* d_in, const int* in_sizes, int n_in,
                              void* d_out, int out_size, void* d_ws, size_t ws_size,
                              hipStream_t stream){
  const float* pf    = (const float*)d_in[0];
  const float* coords= (const float*)d_in[1];
  const float* fB    = (const float*)d_in[2];
  const float* ln_g  = (const float*)d_in[3];
  const float* ln_b  = (const float*)d_in[4];
  const float* Wq    = (const float*)d_in[5];
  const float* Wk    = (const float*)d_in[6];
  const float* Wv    = (const float*)d_in[7];
  const float* Wo    = (const float*)d_in[8];
  const float* bq    = (const float*)d_in[9];
  const float* bk    = (const float*)d_in[10];
  const float* bv    = (const float*)d_in[11];
  const float* bo    = (const float*)d_in[12];
  const float* c1g   = (const float*)d_in[13];
  const float* c1b   = (const float*)d_in[14];
  const float* c1w   = (const float*)d_in[15];
  const float* c1bs  = (const float*)d_in[16];
  const float* cW    = (const float*)d_in[17];
  const float* cB    = (const float*)d_in[18];
  const int*   seg   = (const int*)d_in[19];
  float* out = (float*)d_out;

  // workspace carve-up (~177 MB total)
  char* wsb = (char*)d_ws;
  size_t off = 0;
  auto take = [&](size_t bytes) -> void* {
    void* p = wsb + off;
    off = (off + bytes + 255) & ~(size_t)255;
    return p;
  };
  int*      bucket   = (int*)take((size_t)N_PTS * 4);
  int*      offsets  = (int*)take((size_t)(S_SEG + 1) * 4);
  int*      cursor   = (int*)take((size_t)S_SEG * 4);
  int*      cnt      = (int*)take((size_t)S_SEG * 4);
  unsigned* mm       = (unsigned*)take(6 * 4);
  float*    seg_feat = (float*)take((size_t)S_SEG * F_DIM * 4);
  float*    seg_pos  = (float*)take((size_t)S_SEG * F_DIM * 4);
  float*    norms    = (float*)take((size_t)S_SEG * 4);
  float*    gram     = (float*)take((size_t)S_SEG * S_SEG * 4);
  int*      fpsi     = (int*)take((size_t)K_KEY * 4);
  float*    key_feat = (float*)take((size_t)K_KEY * F_DIM * 4);
  float*    kin      = (float*)take((size_t)K_KEY * F_DIM * 4);
  float*    kh       = (float*)take((size_t)K_KEY * F_DIM * 4);
  float*    vh       = (float*)take((size_t)K_KEY * F_DIM * 4);
  float*    q        = (float*)take((size_t)S_SEG * F_DIM * 4);
  float*    tmp      = (float*)take((size_t)S_SEG * F_DIM * 4);
  float*    qh       = (float*)take((size_t)S_SEG * F_DIM * 4);
  float*    obuf     = (float*)take((size_t)S_SEG * F_DIM * 4);
  float*    att      = (float*)take((size_t)H_HEADS * S_SEG * K_KEY * 4);
  (void)in_sizes; (void)n_in; (void)out_size; (void)ws_size;

  dim3 blk(256);
  const int GM = (S_SEG + 63) / 64;   // 79

  init_kernel<<<dim3((S_SEG + 255) / 256), blk, 0, stream>>>(mm, cnt);
  minmax_kernel<<<dim3(256), blk, 0, stream>>>(coords, mm);
  hist_kernel<<<dim3((N_PTS + 255) / 256), blk, 0, stream>>>(seg, cnt);
  scan_kernel<<<dim3(1), dim3(1024), 0, stream>>>(cnt, offsets, cursor);
  fill_kernel<<<dim3((N_PTS + 255) / 256), blk, 0, stream>>>(seg, offsets, cursor, bucket);
  pool_kernel<<<dim3(S_SEG), blk, 0, stream>>>(coords, pf, fB, bucket, offsets, mm,
                                               seg_feat, seg_pos, norms);
  // Gram (symmetric)
  gemm_nt<<<dim3(GM, GM, 1), blk, 0, stream>>>(seg_pos, F_DIM, 0, seg_pos, F_DIM, 0,
                                               gram, S_SEG, 0, S_SEG, S_SEG, F_DIM, 1.0f, 1);
  fps_kernel<<<dim3(1), dim3(1024), 0, stream>>>(gram, norms, fpsi);
  gather_keys<<<dim3(K_KEY), blk, 0, stream>>>(fpsi, seg_feat, seg_pos, key_feat, kin);
  hipMemcpyAsync(q, seg_feat, (size_t)S_SEG * F_DIM * 4, hipMemcpyDeviceToDevice, stream);

  const float scale = 0.08838834764831845f;  // 1/sqrt(128)
  for (int l = 0; l < 2; ++l){
    const float* Wq_l = Wq + (size_t)l * F_DIM * F_DIM;
    const float* Wk_l = Wk + (size_t)l * F_DIM * F_DIM;
    const float* Wv_l = Wv + (size_t)l * F_DIM * F_DIM;
    const float* Wo_l = Wo + (size_t)l * F_DIM * F_DIM;
    ln_add_kernel<<<dim3(S_SEG), blk, 0, stream>>>(q, seg_pos, ln_g + l * F_DIM,
                                                   ln_b + l * F_DIM, tmp);
    gemm_nn<<<dim3(GM, 8, 1), blk, 0, stream>>>(tmp, 512, 0, Wq_l, 512, 0, bq + l * 512,
                                                nullptr, 0, qh, 512, 0, S_SEG, 512, 512);
    gemm_nn<<<dim3(8, 8, 1), blk, 0, stream>>>(kin, 512, 0, Wk_l, 512, 0, bk + l * 512,
                                               nullptr, 0, kh, 512, 0, 512, 512, 512);
    gemm_nn<<<dim3(8, 8, 1), blk, 0, stream>>>(key_feat, 512, 0, Wv_l, 512, 0, bv + l * 512,
                                               nullptr, 0, vh, 512, 0, 512, 512, 512);
    // scores (batched over heads via z)
    gemm_nt<<<dim3(GM, 8, H_HEADS), blk, 0, stream>>>(qh, 512, (size_t)DH, kh, 512, (size_t)DH,
                                                      att, 512, (size_t)S_SEG * 512,
                                                      S_SEG, 512, DH, scale, 0);
    softmax_kernel<<<dim3(H_HEADS * S_SEG), blk, 0, stream>>>(att);
    // PV (batched over heads)
    gemm_nn<<<dim3(GM, 2, H_HEADS), blk, 0, stream>>>(att, 512, (size_t)S_SEG * 512,
                                                      vh, 512, (size_t)DH, nullptr, nullptr, 0,
                                                      obuf, 512, (size_t)DH, S_SEG, DH, 512);
    // output proj + residual (in-place on q: each element read once then written)
    gemm_nn<<<dim3(GM, 8, 1), blk, 0, stream>>>(obuf, 512, 0, Wo_l, 512, 0, bo + l * 512,
                                                q, 512, q, 512, 0, S_SEG, 512, 512);
  }
  final_kernel<<<dim3((N_PTS + 63) / 64), blk, 0, stream>>>(pf, q, seg, c1g, c1b, c1w, c1bs,
                                                            cW, cB, out);
}